// Round 1
// baseline (2025.359 us; speedup 1.0000x reference)
//
#include <hip/hip_runtime.h>
#include <cmath>

#define BB_   1024
#define TT_   512
#define DD_   16
#define HH_   30
#define LL_   10

// LDS layout (floats):
//   weights, chunk-of-4: layer0: 12 chunks x [30][4]  (row = [x(16) | ownh(30) | pad2])
//                        layers 1..9: 15 chunks x [30][4] (row = [inh(30) | ownh(30)], 60 exact)
//   layer base: l==0 -> 0 ; l>=1 -> 1440 + (l-1)*1800
#define WFLOATS 17640
// vbuf per batch: [0..47] layer0 vec (x16|own30|pad2), then 9 rows of 60 ([in30|own30])
#define VROW    588
#define NB      4     // batches per 128-thread block

__device__ __forceinline__ float tanh_fast(float x) {
    // tanh(x) = 1 - 2/(exp(2x)+1); saturates correctly at +-inf
    float e = __expf(2.0f * x);
    return 1.0f - 2.0f * __builtin_amdgcn_rcpf(e + 1.0f);
}

__global__ __launch_bounds__(128) void rnn_fused(
    const float* __restrict__ x,   const float* __restrict__ wi0,
    const float* __restrict__ wih, const float* __restrict__ whh,
    const float* __restrict__ bih, const float* __restrict__ bhh,
    const float* __restrict__ fcw, const float* __restrict__ fcb,
    float* __restrict__ out)
{
    extern __shared__ float sm[];
    float* wlds = sm;            // WFLOATS
    float* vbuf = sm + WFLOATS;  // NB * VROW

    const int tid = threadIdx.x;
    const int bb  = tid >> 5;          // batch slot in block (0..3)
    const int j   = tid & 31;          // output neuron (0..31, 30 active)
    const int jm  = (j < HH_) ? j : HH_ - 1;
    const int batch = blockIdx.x * NB + bb;

    // ---- stage weights into LDS (chunk-of-4 layout) ----
    for (int idx = tid; idx < WFLOATS; idx += 128) {
        int l, r;
        if (idx < 1440) { l = 0; r = idx; }
        else            { l = 1 + (idx - 1440) / 1800; r = (idx - 1440) % 1800; }
        const int c  = r / 120;        // chunk
        const int w  = r % 120;
        const int jj = w >> 2;         // row 0..29
        const int e  = w & 3;
        const int kf = c * 4 + e;      // position in combined row
        float val;
        if (l == 0) {
            if (kf < 16)      val = wi0[jj * DD_ + kf];
            else if (kf < 46) val = whh[jj * HH_ + (kf - 16)];
            else              val = 0.0f;
        } else {
            if (kf < 30) val = wih[(l - 1) * 900 + jj * 30 + kf];
            else         val = whh[l * 900 + jj * 30 + (kf - 30)];
        }
        wlds[idx] = val;
    }
    // zero hidden-state / staging buffers
    for (int idx = tid; idx < NB * VROW; idx += 128) vbuf[idx] = 0.0f;

    // per-lane constants
    float bcomb[LL_];
    #pragma unroll
    for (int l = 0; l < LL_; ++l)
        bcomb[l] = (j < HH_) ? (bih[l * HH_ + j] + bhh[l * HH_ + j]) : 0.0f;
    const float fw = (j < HH_) ? fcw[j] : 0.0f;
    const float fb = fcb[0];

    __syncthreads();

    const float* xrow = x + (size_t)batch * TT_ * DD_;
    float* vb = vbuf + bb * VROW;
    float hlast = 0.0f;

    // prefetch x_0
    float xv = (j < DD_) ? xrow[j] : 0.0f;

    for (int t = 0; t < TT_; ++t) {
        // stage x_t into layer-0 vector; prefetch x_{t+1} (covered by compute)
        if (j < DD_) {
            vb[j] = xv;
            int tn = (t + 1 < TT_) ? t + 1 : t;
            xv = xrow[tn * DD_ + j];
        }

        // ---- layer 0: 12 chunks over [x(16) | own h(30) | pad2] ----
        {
            float a0 = 0.f, a1 = 0.f, a2 = 0.f, a3 = 0.f;
            #pragma unroll
            for (int c = 0; c < 12; ++c) {
                const float4 wv = *(const float4*)(wlds + c * 120 + jm * 4);
                const float4 vv = *(const float4*)(vb + c * 4);
                a0 = fmaf(wv.x, vv.x, a0);
                a1 = fmaf(wv.y, vv.y, a1);
                a2 = fmaf(wv.z, vv.z, a2);
                a3 = fmaf(wv.w, vv.w, a3);
            }
            const float h = tanh_fast(bcomb[0] + ((a0 + a1) + (a2 + a3)));
            if (j < HH_) { vb[16 + j] = h; vb[48 + j] = h; }  // own slot (t+1), next-layer in slot (t)
        }

        // ---- layers 1..9: 15 chunks over [in h(30) | own h(30)] ----
        #pragma unroll
        for (int l = 1; l < LL_; ++l) {
            const float* wl = wlds + 1440 + (l - 1) * 1800;
            float* vr = vb + 48 + (l - 1) * 60;
            float a0 = 0.f, a1 = 0.f, a2 = 0.f, a3 = 0.f;
            #pragma unroll
            for (int c = 0; c < 15; ++c) {
                const float4 wv = *(const float4*)(wl + c * 120 + jm * 4);
                const float4 vv = *(const float4*)(vr + c * 4);
                a0 = fmaf(wv.x, vv.x, a0);
                a1 = fmaf(wv.y, vv.y, a1);
                a2 = fmaf(wv.z, vv.z, a2);
                a3 = fmaf(wv.w, vv.w, a3);
            }
            const float h = tanh_fast(bcomb[l] + ((a0 + a1) + (a2 + a3)));
            if (j < HH_) {
                vr[30 + j] = h;                    // own slot for t+1
                if (l < LL_ - 1) vr[60 + j] = h;   // input slot of layer l+1 at t
            }
            if (l == LL_ - 1) hlast = h;
        }
    }

    // ---- fc on last hidden of layer 9: out[b] = sum_j fcw[j]*h[j] + fcb ----
    float v = (j < HH_) ? hlast * fw : 0.0f;
    #pragma unroll
    for (int s = 16; s > 0; s >>= 1) v += __shfl_xor(v, s);
    if (j == 0) out[batch] = v + fb;
}

extern "C" void kernel_launch(void* const* d_in, const int* in_sizes, int n_in,
                              void* d_out, int out_size, void* d_ws, size_t ws_size,
                              hipStream_t stream) {
    const float* x   = (const float*)d_in[0];
    const float* wi0 = (const float*)d_in[1];
    const float* wih = (const float*)d_in[2];
    const float* whh = (const float*)d_in[3];
    const float* bih = (const float*)d_in[4];
    const float* bhh = (const float*)d_in[5];
    const float* fcw = (const float*)d_in[6];
    const float* fcb = (const float*)d_in[7];
    float* out = (float*)d_out;

    const size_t lds_bytes = (size_t)(WFLOATS + NB * VROW) * sizeof(float); // 79968 B
    hipFuncSetAttribute((const void*)rnn_fused,
                        hipFuncAttributeMaxDynamicSharedMemorySize,
                        (int)lds_bytes);

    rnn_fused<<<BB_ / NB, 128, lds_bytes, stream>>>(x, wi0, wih, whh, bih, bhh,
                                                    fcw, fcb, out);
}

// Round 2
// 399.864 us; speedup vs baseline: 5.0651x; 5.0651x over previous
//
#include <hip/hip_runtime.h>

#define TT 512
#define DD 16
#define HH 30
#define LL 10
#define NBATCH 4              // batches per block
#define ROWF 68               // floats per v-row: [in 0..30 | own 30..60 | pad]
#define PHASES (TT + LL - 1)  // 521

__device__ __forceinline__ float tanh_fast(float x) {
    // tanh(x) = 1 - 2/(exp(2x)+1); saturates correctly at +-inf
    float e = __expf(2.0f * x);
    return 1.0f - 2.0f * __builtin_amdgcn_rcpf(e + 1.0f);
}

__global__ __launch_bounds__(640, 3) void rnn_pipe(
    const float* __restrict__ x,   const float* __restrict__ wi0,
    const float* __restrict__ wih, const float* __restrict__ whh,
    const float* __restrict__ bih, const float* __restrict__ bhh,
    const float* __restrict__ fcw, const float* __restrict__ fcb,
    float* __restrict__ out)
{
    // parity-double-buffered activation rows, one per (layer, batch-slot)
    __shared__ __align__(16) float vrow[2][LL][NBATCH][ROWF];

    const int tid  = threadIdx.x;
    const int l    = tid >> 6;        // wave index == layer index
    const int lane = tid & 63;
    const int bb   = lane >> 4;       // batch slot 0..3
    const int g    = lane & 15;       // neuron group (g<15 active for compute)
    const int gm   = (g < 15) ? g : 14;
    const int j0   = 2 * gm, j1 = 2 * gm + 1;
    const int batch = blockIdx.x * NBATCH + bb;

    // ---- weights for this wave's layer: rows j0, j1 of [in(30) | own(30)] ----
    float w0[60], w1[60];
    #pragma unroll
    for (int k = 0; k < HH; ++k) {
        float a, b;
        if (l == 0) {
            a = (k < DD) ? wi0[j0 * DD + k] : 0.0f;
            b = (k < DD) ? wi0[j1 * DD + k] : 0.0f;
        } else {
            a = wih[(l - 1) * 900 + j0 * HH + k];
            b = wih[(l - 1) * 900 + j1 * HH + k];
        }
        w0[k] = a; w1[k] = b;
    }
    #pragma unroll
    for (int k = 0; k < HH; ++k) {
        w0[HH + k] = whh[l * 900 + j0 * HH + k];
        w1[HH + k] = whh[l * 900 + j1 * HH + k];
    }
    const float bc0 = bih[l * HH + j0] + bhh[l * HH + j0];
    const float bc1 = bih[l * HH + j1] + bhh[l * HH + j1];
    float fw0 = 0.f, fw1 = 0.f, fbv = 0.f;
    if (l == LL - 1) { fw0 = fcw[j0]; fw1 = fcw[j1]; fbv = fcb[0]; }

    // ---- zero all activation rows (h(-1)=0; in-slots 16..30 of layer 0 stay 0) ----
    for (int i = tid; i < 2 * LL * NBATCH * ROWF; i += 640)
        ((float*)vrow)[i] = 0.0f;
    __syncthreads();

    // ---- prologue: wave 0 stages x(0) into parity-1 in-slot, prefetch x(1) ----
    const float* xb = x + (size_t)batch * TT * DD;
    float xreg = 0.0f;
    if (l == 0) {
        vrow[1][0][bb][g] = xb[g];          // x(0), all 64 lanes (g<16 per bb)
        xreg = xb[1 * DD + g];              // prefetch x(1)
    }
    // no barrier needed: only wave 0 reads layer-0 in-slot at phase 0 (same wave)

    float hl0 = 0.0f, hl1 = 0.0f;           // wave 9 keeps h(511) for FC

    for (int p = 0; p < PHASES; ++p) {
        const int t  = p - l;
        const int q  = (p + 1) & 1;         // read parity  == (p-1)&1
        const int wp = p & 1;               // write parity

        if (t >= 0 && t < TT) {
            const float* vr = &vrow[q][l][bb][0];
            float a0 = 0.0f, a1 = 0.0f;
            #pragma unroll
            for (int c = 0; c < 15; ++c) {
                const float4 vv = *(const float4*)(vr + 4 * c);
                a0 = fmaf(w0[4*c+0], vv.x, a0);
                a1 = fmaf(w1[4*c+0], vv.x, a1);
                a0 = fmaf(w0[4*c+1], vv.y, a0);
                a1 = fmaf(w1[4*c+1], vv.y, a1);
                a0 = fmaf(w0[4*c+2], vv.z, a0);
                a1 = fmaf(w1[4*c+2], vv.z, a1);
                a0 = fmaf(w0[4*c+3], vv.w, a0);
                a1 = fmaf(w1[4*c+3], vv.w, a1);
            }
            const float h0 = tanh_fast(bc0 + a0);
            const float h1 = tanh_fast(bc1 + a1);
            if (g < 15) {
                // own slot for t+1 (floats 30..60)
                *(float2*)&vrow[wp][l][bb][HH + 2 * gm] = make_float2(h0, h1);
                // next layer's in-slot for this t (floats 0..30)
                if (l < LL - 1)
                    *(float2*)&vrow[wp][l + 1][bb][2 * gm] = make_float2(h0, h1);
            }
            hl0 = h0; hl1 = h1;
        }

        // wave 0 stages x(p+1) into write-parity in-slot; prefetch x(p+2)
        if (l == 0 && p + 1 < TT) {
            vrow[wp][0][bb][g] = xreg;
            if (p + 2 < TT) xreg = xb[(p + 2) * DD + g];
        }

        __syncthreads();
    }

    // ---- FC on h_9(511): out[b] = sum_j fcw[j] h[j] + fcb ----
    if (l == LL - 1) {
        float v = (g < 15) ? (hl0 * fw0 + hl1 * fw1) : 0.0f;
        v += __shfl_xor(v, 1);
        v += __shfl_xor(v, 2);
        v += __shfl_xor(v, 4);
        v += __shfl_xor(v, 8);
        if (g == 0) out[batch] = v + fbv;
    }
}

extern "C" void kernel_launch(void* const* d_in, const int* in_sizes, int n_in,
                              void* d_out, int out_size, void* d_ws, size_t ws_size,
                              hipStream_t stream) {
    const float* x   = (const float*)d_in[0];
    const float* wi0 = (const float*)d_in[1];
    const float* wih = (const float*)d_in[2];
    const float* whh = (const float*)d_in[3];
    const float* bih = (const float*)d_in[4];
    const float* bhh = (const float*)d_in[5];
    const float* fcw = (const float*)d_in[6];
    const float* fcb = (const float*)d_in[7];
    float* out = (float*)d_out;

    rnn_pipe<<<1024 / NBATCH, 640, 0, stream>>>(x, wi0, wih, whh, bih, bhh,
                                                fcw, fcb, out);
}

// Round 3
// 286.552 us; speedup vs baseline: 7.0680x; 1.3954x over previous
//
#include <hip/hip_runtime.h>

#define TT 512
#define DD 16
#define HH 30
#define LL 10
#define NB 4                  // batches per block
#define C  4                  // timesteps per phase (chunk)
#define TCH (TT / C)          // 128 chunks
#define PH (TCH + LL - 1)     // 137 phases
#define ROWH 40               // halfs per row (80 B): [data 0..31 | pad]

typedef _Float16 h2 __attribute__((ext_vector_type(2)));
typedef _Float16 h4 __attribute__((ext_vector_type(4)));

__device__ __forceinline__ float tanh_fast(float x) {
    // tanh(x) = 1 - 2/(exp(2x)+1); saturates correctly at +-inf
    float e = __expf(2.0f * x);
    return 1.0f - 2.0f * __builtin_amdgcn_rcpf(e + 1.0f);
}

#if __has_builtin(__builtin_amdgcn_fdot2)
#define DOT2(a, b, c) __builtin_amdgcn_fdot2((a), (b), (c), false)
#else
__device__ __forceinline__ float DOT2(h2 a, h2 b, float c) {
    return fmaf((float)a.x, (float)b.x, fmaf((float)a.y, (float)b.y, c));
}
#endif

__device__ __forceinline__ h2 asH2(unsigned u) {
    union { unsigned u; h2 h; } v; v.u = u; return v.h;
}

__global__ __launch_bounds__(640, 2) void rnn_pipe16(
    const float* __restrict__ x,   const float* __restrict__ wi0,
    const float* __restrict__ wih, const float* __restrict__ whh,
    const float* __restrict__ bih, const float* __restrict__ bhh,
    const float* __restrict__ fcw, const float* __restrict__ fcb,
    float* __restrict__ out)
{
    // act[parity][layer][c][bb]: INPUT row for layer at chunk-timestep c
    //   (layer 0's input rows = x, staged by wave 0). halfs 0..31 data, rest pad.
    // own[layer][bb]: layer's own h (same-wave producer/consumer, no parity).
    __shared__ __align__(16) _Float16 act[2][LL][C][NB][ROWH];
    __shared__ __align__(16) _Float16 own[LL][NB][ROWH];

    const int tid  = threadIdx.x;
    const int l    = tid >> 6;        // wave == layer
    const int lane = tid & 63;
    const int bb   = lane >> 4;       // batch slot 0..3
    const int g    = lane & 15;       // neuron group (g<15 active)
    const int gm   = (g < 15) ? g : 14;
    const int j0   = 2 * gm, j1 = 2 * gm + 1;
    const int batch = blockIdx.x * NB + bb;

    // ---- pack this layer's weight rows j0,j1 into h2 registers ----
    // words 0..15: input weights (layer0: 16 x-weights; else 30 h-weights + pad)
    // words 16..31: own-recurrence weights (30 + pad)
    h2 w0p[32], w1p[32];
    #pragma unroll
    for (int c = 0; c < 16; ++c) {
        const int k0 = 2 * c, k1 = 2 * c + 1;
        float a0 = 0.f, a1 = 0.f, b0 = 0.f, b1 = 0.f;
        if (l == 0) {
            if (k0 < DD) { a0 = wi0[j0 * DD + k0]; b0 = wi0[j1 * DD + k0]; }
            if (k1 < DD) { a1 = wi0[j0 * DD + k1]; b1 = wi0[j1 * DD + k1]; }
        } else {
            if (k0 < HH) { a0 = wih[(l-1)*900 + j0*HH + k0]; b0 = wih[(l-1)*900 + j1*HH + k0]; }
            if (k1 < HH) { a1 = wih[(l-1)*900 + j0*HH + k1]; b1 = wih[(l-1)*900 + j1*HH + k1]; }
        }
        w0p[c] = h2{(_Float16)a0, (_Float16)a1};
        w1p[c] = h2{(_Float16)b0, (_Float16)b1};
    }
    #pragma unroll
    for (int c = 0; c < 16; ++c) {
        const int k0 = 2 * c, k1 = 2 * c + 1;
        float a0 = 0.f, a1 = 0.f, b0 = 0.f, b1 = 0.f;
        if (k0 < HH) { a0 = whh[l*900 + j0*HH + k0]; b0 = whh[l*900 + j1*HH + k0]; }
        if (k1 < HH) { a1 = whh[l*900 + j0*HH + k1]; b1 = whh[l*900 + j1*HH + k1]; }
        w0p[16 + c] = h2{(_Float16)a0, (_Float16)a1};
        w1p[16 + c] = h2{(_Float16)b0, (_Float16)b1};
    }
    const float bc0 = bih[l * HH + j0] + bhh[l * HH + j0];
    const float bc1 = bih[l * HH + j1] + bhh[l * HH + j1];
    float fw0 = 0.f, fw1 = 0.f, fbv = 0.f;
    if (l == LL - 1) { fw0 = fcw[j0]; fw1 = fcw[j1]; fbv = fcb[0]; }

    // ---- zero LDS (pad slots must be true zeros forever; h(-1)=0) ----
    {
        unsigned* za = (unsigned*)&act[0][0][0][0][0];
        for (int i = tid; i < 2*LL*C*NB*ROWH/2; i += 640) za[i] = 0u;
        unsigned* zo = (unsigned*)&own[0][0][0];
        for (int i = tid; i < LL*NB*ROWH/2; i += 640) zo[i] = 0u;
    }
    __syncthreads();

    // ---- x staging lane map (wave 0 only): lane = ((sc*4)+sbb)*4 + sq ----
    const int sq  = lane & 3;          // quarter of the 16 x-values
    const int sbb = (lane >> 2) & 3;   // batch slot
    const int sc  = lane >> 4;         // chunk-timestep 0..3
    const int batch_s = blockIdx.x * NB + sbb;
    const float4* xb4 = (const float4*)x;

    // prestage x[t=0..3] into parity-1 rows (read by wave 0 itself at p=0)
    if (l == 0) {
        float4 v = xb4[batch_s * TT * 4 + sc * 4 + sq];
        h4 hx; hx.x = (_Float16)v.x; hx.y = (_Float16)v.y;
        hx.z = (_Float16)v.z; hx.w = (_Float16)v.w;
        *(h4*)&act[1][0][sc][sbb][4 * sq] = hx;
    }

    float hl0 = 0.f, hl1 = 0.f;        // wave 9 keeps h(T-1) for FC

    for (int p = 0; p < PH; ++p) {
        const int q  = (p + 1) & 1;    // read parity
        const int wp = p & 1;          // write parity
        const int pt = p - l;          // this wave's chunk index

        // wave 0: issue next phase's x loads early (latency hides under compute)
        float4 xv;
        const bool dost = (l == 0) && (p + 1 < TCH);
        if (dost)
            xv = xb4[batch_s * TT * 4 + ((p + 1) * C + sc) * 4 + sq];

        if (0 <= pt && pt < TCH) {
            #pragma unroll
            for (int cc = 0; cc < C; ++cc) {
                const uint4* ir = (const uint4*)&act[q][l][cc][bb][0];
                const uint4 A = ir[0], B = ir[1], Cw = ir[2], Dw = ir[3];
                const uint4* orr = (const uint4*)&own[l][bb][0];
                const uint4 E = orr[0], F = orr[1], G = orr[2], Hh = orr[3];
                const unsigned wv[32] = {
                    A.x,A.y,A.z,A.w,  B.x,B.y,B.z,B.w,
                    Cw.x,Cw.y,Cw.z,Cw.w, Dw.x,Dw.y,Dw.z,Dw.w,
                    E.x,E.y,E.z,E.w,  F.x,F.y,F.z,F.w,
                    G.x,G.y,G.z,G.w,  Hh.x,Hh.y,Hh.z,Hh.w };
                float a0 = bc0, a1 = bc1;
                #pragma unroll
                for (int c = 0; c < 32; ++c) {
                    const h2 vv = asH2(wv[c]);
                    a0 = DOT2(w0p[c], vv, a0);
                    a1 = DOT2(w1p[c], vv, a1);
                }
                const float h0 = tanh_fast(a0);
                const float h1 = tanh_fast(a1);
                h2 hp; hp.x = (_Float16)h0; hp.y = (_Float16)h1;
                if (g < 15) {
                    *(h2*)&own[l][bb][2 * gm] = hp;             // own h for t+1
                    if (l < LL - 1)
                        *(h2*)&act[wp][l + 1][cc][bb][2 * gm] = hp; // next layer's input
                }
                hl0 = h0; hl1 = h1;
            }
        }

        // wave 0: convert + write staged x rows for phase p+1
        if (dost) {
            h4 hx; hx.x = (_Float16)xv.x; hx.y = (_Float16)xv.y;
            hx.z = (_Float16)xv.z; hx.w = (_Float16)xv.w;
            *(h4*)&act[wp][0][sc][sbb][4 * sq] = hx;
        }

        __syncthreads();
    }

    // ---- FC on h_{L-1}(T-1): out[b] = sum_j fcw[j] h[j] + fcb ----
    if (l == LL - 1) {
        float v = (g < 15) ? fmaf(hl0, fw0, hl1 * fw1) : 0.f;
        v += __shfl_xor(v, 1);
        v += __shfl_xor(v, 2);
        v += __shfl_xor(v, 4);
        v += __shfl_xor(v, 8);
        if (g == 0) out[batch] = v + fbv;
    }
}

extern "C" void kernel_launch(void* const* d_in, const int* in_sizes, int n_in,
                              void* d_out, int out_size, void* d_ws, size_t ws_size,
                              hipStream_t stream) {
    const float* x   = (const float*)d_in[0];
    const float* wi0 = (const float*)d_in[1];
    const float* wih = (const float*)d_in[2];
    const float* whh = (const float*)d_in[3];
    const float* bih = (const float*)d_in[4];
    const float* bhh = (const float*)d_in[5];
    const float* fcw = (const float*)d_in[6];
    const float* fcb = (const float*)d_in[7];
    float* out = (float*)d_out;

    rnn_pipe16<<<1024 / NB, 640, 0, stream>>>(x, wi0, wih, whh, bih, bhh,
                                              fcw, fcb, out);
}